// Round 13
// baseline (53.894 us; speedup 1.0000x reference)
//
#include <hip/hip_runtime.h>

// B=8192, D=1024, C=90, K=16.
// R13: two dispatch nodes, deterministic.
//  (1) bin_labels (proven ballot-binning) + zeroes the 8 XCD accumulators
//      and done counters (plain stores; kernel-boundary makes them visible).
//  (2) octo_dots: block = OCTET (8 same-class samples); wave = D-quarter.
//      Centers read once per 8 samples (67 MB L2, XCD-pinned classes via
//      b&7). Per wave: 8 x float4 loads, 16 center loads, 8x REDUCE16,
//      LDS combine, 2-wave epilogue. Tail: per-block fixed-point int64
//      atomicAdd onto xacc[8] (spread addresses), per-group done counter
//      (ACQ_REL agent-scope, no threadfence), 8-arrival second level; the
//      last group's last block sums xacc[0..7] in fixed order -> out.
//      Integer adds commute -> bit-deterministic output.

#define B_SAMP  8192
#define K_SUB   16
#define C_CLS   90
#define LISTCAP 192             // per-class capacity (mean 91, ~10 sigma)
#define F4_ROW  256             // float4 per D=1024 row
#define TSLOT   192             // octet slots per XCD group (worst ~155)
#define NBLK    (8 * TSLOT)     // 1536
#define SCALE   4398046511104.0 // 2^42

// ws layout (bytes)
#define OFF_COUNTS 0            // 90 ints
#define OFF_LISTS  4096         // 90*192 ints
#define OFF_XACC   (1u << 20)   // 8 x u64 (one per XCD group, 16B apart)
#define OFF_DONE   ((1u << 20) + 256)   // 8 x u32 (16B apart)
#define OFF_DONE8  ((1u << 20) + 512)   // 1 x u32

template <int CTRL>
__device__ __forceinline__ float dpp_qperm(float v) {
    return __int_as_float(__builtin_amdgcn_update_dpp(
        0, __float_as_int(v), CTRL, 0xF, 0xF, true));
}

// 16-lane-group epilogue (verified R6-R12).
__device__ __forceinline__ float sample_loss16(float r, int kk)
{
    const float d = 1.0f - r;
    float S = d;
    S += __shfl_xor(S, 1, 64);
    S += __shfl_xor(S, 2, 64);
    S += __shfl_xor(S, 4, 64);
    S += __shfl_xor(S, 8, 64);
    float dmin = d;
    dmin = fminf(dmin, __shfl_xor(dmin, 1, 64));
    dmin = fminf(dmin, __shfl_xor(dmin, 2, 64));
    dmin = fminf(dmin, __shfl_xor(dmin, 4, 64));
    dmin = fminf(dmin, __shfl_xor(dmin, 8, 64));
    int cand = (d == dmin) ? kk : 99;      // first-min == jnp.argmin
    cand = min(cand, __shfl_xor(cand, 1, 64));
    cand = min(cand, __shfl_xor(cand, 2, 64));
    cand = min(cand, __shfl_xor(cand, 4, 64));
    cand = min(cand, __shfl_xor(cand, 8, 64));
    const float inv = 1.0f / S;
    float t = (kk == cand) ? (d * d * inv)            // term1
                           : ((1.0f - d * inv) * d);  // term2
    t += __shfl_xor(t, 1, 64);
    t += __shfl_xor(t, 2, 64);
    t += __shfl_xor(t, 4, 64);
    t += __shfl_xor(t, 8, 64);
    return t;
}

// ---------------- Kernel 1: bin labels by class (90 blocks) ----------------
__global__ __launch_bounds__(256) void bin_labels(
    const int* __restrict__ labels,
    int*       __restrict__ counts,
    int*       __restrict__ lists,
    unsigned long long* __restrict__ xacc,
    unsigned int*       __restrict__ done,
    unsigned int*       __restrict__ done8)
{
    const int c    = blockIdx.x;
    const int tid  = threadIdx.x;
    const int wave = tid >> 6;
    const int lane = tid & 63;
    __shared__ int wcnt[4];

    if (c == 0) {                       // zero tail state (visible at kernel end)
        if (tid < 8)  xacc[tid * 2] = 0ull;     // 16B apart
        if (tid < 8)  done[tid * 4] = 0u;       // 16B apart
        if (tid == 8) *done8 = 0u;
    }

    const int4* lv = reinterpret_cast<const int4*>(labels);

    int4 seg[8];
    int cnt = 0;
#pragma unroll
    for (int it = 0; it < 8; ++it) {
        seg[it] = lv[wave * 512 + it * 64 + lane];
        cnt += (seg[it].x == c) + (seg[it].y == c) + (seg[it].z == c) + (seg[it].w == c);
    }
#pragma unroll
    for (int off = 32; off > 0; off >>= 1) cnt += __shfl_xor(cnt, off, 64);
    if (lane == 0) wcnt[wave] = cnt;
    __syncthreads();

    int base = 0;
    for (int w = 0; w < wave; ++w) base += wcnt[w];
    const int total = wcnt[0] + wcnt[1] + wcnt[2] + wcnt[3];

#pragma unroll
    for (int it = 0; it < 8; ++it) {
        const int idx0 = (wave * 512 + it * 64 + lane) * 4;
        const int ls[4] = { seg[it].x, seg[it].y, seg[it].z, seg[it].w };
#pragma unroll
        for (int u = 0; u < 4; ++u) {
            const bool hit = (ls[u] == c);
            const unsigned long long m = __ballot(hit);
            if (hit) {
                const int p = base + (int)__popcll(m & ((1ull << lane) - 1ull));
                if (p < LISTCAP) lists[c * LISTCAP + p] = idx0 + u;
            }
            base += (int)__popcll(m);
        }
    }
    if (tid == 0) counts[c] = (total <= LISTCAP) ? total : LISTCAP;
}

// -------- Kernel 2: octet dots + loss + spread fixed-point tail --------
__global__ __launch_bounds__(256) void octo_dots(
    const float* __restrict__ x,
    const float* __restrict__ centers,
    const int*   __restrict__ counts,
    const int*   __restrict__ lists,
    unsigned long long* __restrict__ xacc,
    unsigned int*       __restrict__ done,
    unsigned int*       __restrict__ done8,
    float*              __restrict__ out)
{
    const int b    = blockIdx.x;
    const int g    = b & 7;                 // XCD group: classes c == g (mod 8)
    const int t    = b >> 3;                // octet slot within group
    const int tid  = threadIdx.x;
    const int wv   = tid >> 6;              // D-quarter index 0..3
    const int lane = tid & 63;

    __shared__ float sdots[4][8][17];       // [quarter][sample][k], padded
    __shared__ float wsum[2];

    // ---- 16-lane register scan: octet t -> (class, offset) ----
    const int cl  = g + 8 * lane;                       // lane<12 relevant
    const int n_l = (lane < 12 && cl < C_CLS) ? counts[cl] : 0;
    const int o_l = (n_l + 7) >> 3;                     // octets in this class
    int inc = o_l;
#pragma unroll
    for (int off = 1; off < 16; off <<= 1) {
        const int v = __shfl_up(inc, off, 64);
        if (lane >= off) inc += v;
    }
    const int Qg  = __shfl(inc, 15, 64);                // total octets in group
    const int exc = inc - o_l;

    long long qfix = 0ll;                               // tid 0's block loss

    if (t < Qg) {
        const bool hit = (lane < 16) && (o_l > 0) && (t >= exc) && (t < inc);
        const unsigned long long m = __ballot(hit);
        const int ls   = (int)__ffsll(m) - 1;
        const int cls  = g + 8 * ls;
        const int ooff = t - __shfl(exc, ls, 64);
        const int cntc = __shfl(n_l, ls, 64);
        const int base = ooff * 8;                      // < cntc always

        const int4* lp = reinterpret_cast<const int4*>(lists + cls * LISTCAP + base);
        const int4 g0 = lp[0];
        const int4 g1 = lp[1];
        int id[8];
        id[0] = g0.x;
        id[1] = (base + 1 < cntc) ? g0.y : g0.x;
        id[2] = (base + 2 < cntc) ? g0.z : g0.x;
        id[3] = (base + 3 < cntc) ? g0.w : g0.x;
        id[4] = (base + 4 < cntc) ? g1.x : g0.x;
        id[5] = (base + 5 < cntc) ? g1.y : g0.x;
        id[6] = (base + 6 < cntc) ? g1.z : g0.x;
        id[7] = (base + 7 < cntc) ? g1.w : g0.x;

        // x: this wave's D-quarter of the 8 rows (8 loads, all in flight)
        const float4* xv = reinterpret_cast<const float4*>(x) + (wv * 64 + lane);
        float4 xr[8];
#pragma unroll
        for (int s = 0; s < 8; ++s)
            xr[s] = xv[(size_t)id[s] * F4_ROW];

        const float4* cb = reinterpret_cast<const float4*>(centers)
                         + ((size_t)cls * K_SUB * F4_ROW + wv * 64 + lane);

        const bool b0 = (lane & 1) != 0;
        const bool b1 = (lane & 2) != 0;
        const bool b2 = (lane & 4) != 0;
        const bool b3 = (lane & 8) != 0;
        const int kmap = 8 * (lane & 1) + 4 * ((lane >> 1) & 1)
                       + 2 * ((lane >> 2) & 1) + ((lane >> 3) & 1);

#define REDUCE16(A, OUT)                                                      \
    {                                                                         \
        _Pragma("unroll")                                                     \
        for (int jj = 0; jj < 8; ++jj) {                                      \
            const float send = b0 ? A[jj] : A[jj + 8];                        \
            const float recv = dpp_qperm<0xB1>(send);       /* xor 1 */       \
            A[jj] = (b0 ? A[jj + 8] : A[jj]) + recv;                          \
        }                                                                     \
        _Pragma("unroll")                                                     \
        for (int jj = 0; jj < 4; ++jj) {                                      \
            const float send = b1 ? A[jj] : A[jj + 4];                        \
            const float recv = dpp_qperm<0x4E>(send);       /* xor 2 */       \
            A[jj] = (b1 ? A[jj + 4] : A[jj]) + recv;                          \
        }                                                                     \
        _Pragma("unroll")                                                     \
        for (int jj = 0; jj < 2; ++jj) {                                      \
            const float send = b2 ? A[jj] : A[jj + 2];                        \
            const float recv = __shfl_xor(send, 4, 64);                       \
            A[jj] = (b2 ? A[jj + 2] : A[jj]) + recv;                          \
        }                                                                     \
        {                                                                     \
            const float send = b3 ? A[0] : A[1];                              \
            const float recv = __shfl_xor(send, 8, 64);                       \
            A[0] = (b3 ? A[1] : A[0]) + recv;                                 \
        }                                                                     \
        A[0] += __shfl_xor(A[0], 16, 64);                                     \
        A[0] += __shfl_xor(A[0], 32, 64);                                     \
        OUT = A[0];                                                           \
    }

        // 4 k-groups; per group: 4 center loads feed ALL 8 samples.
#pragma unroll
        for (int kq = 0; kq < 4; ++kq) {
            float4 q4[4];
#pragma unroll
            for (int kk = 0; kk < 4; ++kk)
                q4[kk] = cb[(kq * 4 + kk) * F4_ROW];

            float A[16];
#pragma unroll
            for (int kk = 0; kk < 4; ++kk) {
#pragma unroll
                for (int s = 0; s < 4; ++s) {
                    float v = xr[s].x * q4[kk].x;
                    v = fmaf(xr[s].y, q4[kk].y, v);
                    v = fmaf(xr[s].z, q4[kk].z, v);
                    v = fmaf(xr[s].w, q4[kk].w, v);
                    A[s * 4 + kk] = v;
                }
            }
            float rA;
            REDUCE16(A, rA)
            if (lane < 16) sdots[wv][kmap >> 2][kq * 4 + (kmap & 3)] = rA;

            float B[16];
#pragma unroll
            for (int kk = 0; kk < 4; ++kk) {
#pragma unroll
                for (int s = 0; s < 4; ++s) {
                    float v = xr[4 + s].x * q4[kk].x;
                    v = fmaf(xr[4 + s].y, q4[kk].y, v);
                    v = fmaf(xr[4 + s].z, q4[kk].z, v);
                    v = fmaf(xr[4 + s].w, q4[kk].w, v);
                    B[s * 4 + kk] = v;
                }
            }
            float rB;
            REDUCE16(B, rB)
            if (lane < 16) sdots[wv][4 + (kmap >> 2)][kq * 4 + (kmap & 3)] = rB;
        }
#undef REDUCE16

        __syncthreads();

        // epilogue: waves 0-1 handle 4 samples each (16 lanes per sample)
        if (wv < 2) {
            const int s  = wv * 4 + (lane >> 4);
            const int kk = lane & 15;
            const float r = sdots[0][s][kk] + sdots[1][s][kk]
                          + sdots[2][s][kk] + sdots[3][s][kk];
            const float gate = (base + s < cntc) ? 1.0f : 0.0f;
            float wl = sample_loss16(r, kk) * gate;
            wl += __shfl_xor(wl, 16, 64);
            wl += __shfl_xor(wl, 32, 64);
            if (lane == 0) wsum[wv] = wl;
        }
        __syncthreads();

        if (tid == 0)
            qfix = (long long)__double2ll_rn((double)(wsum[0] + wsum[1]) * SCALE);
    }

    // ---- tail: spread atomics, ACQ_REL ordering, no threadfence ----
    if (tid == 0) {
        if (qfix != 0ll)
            __hip_atomic_fetch_add(&xacc[g * 2], (unsigned long long)qfix,
                                   __ATOMIC_RELAXED, __HIP_MEMORY_SCOPE_AGENT);
        const unsigned int old =
            __hip_atomic_fetch_add(&done[g * 4], 1u,
                                   __ATOMIC_ACQ_REL, __HIP_MEMORY_SCOPE_AGENT);
        if (old == (unsigned int)(TSLOT - 1)) {
            const unsigned int old8 =
                __hip_atomic_fetch_add(done8, 1u,
                                       __ATOMIC_ACQ_REL, __HIP_MEMORY_SCOPE_AGENT);
            if (old8 == 7u) {
                unsigned long long tot = 0ull;
#pragma unroll
                for (int g2 = 0; g2 < 8; ++g2)       // fixed order, exact ints
                    tot += __hip_atomic_fetch_add(&xacc[g2 * 2], 0ull,
                                                  __ATOMIC_ACQUIRE,
                                                  __HIP_MEMORY_SCOPE_AGENT);
                out[0] = (float)((double)(long long)tot
                                 * (1.0 / (SCALE * (double)B_SAMP)));
            }
        }
    }
}

extern "C" void kernel_launch(void* const* d_in, const int* in_sizes, int n_in,
                              void* d_out, int out_size, void* d_ws, size_t ws_size,
                              hipStream_t stream)
{
    const float* x       = (const float*)d_in[0];
    const int*   labels  = (const int*)  d_in[1];
    const float* centers = (const float*)d_in[2];
    float*       out     = (float*)d_out;
    char*        ws      = (char*)d_ws;

    int*                counts = (int*)               (ws + OFF_COUNTS);
    int*                lists  = (int*)               (ws + OFF_LISTS);
    unsigned long long* xacc   = (unsigned long long*)(ws + OFF_XACC);
    unsigned int*       done   = (unsigned int*)      (ws + OFF_DONE);
    unsigned int*       done8  = (unsigned int*)      (ws + OFF_DONE8);

    bin_labels<<<C_CLS, 256, 0, stream>>>(labels, counts, lists, xacc, done, done8);
    octo_dots <<<NBLK,  256, 0, stream>>>(x, centers, counts, lists,
                                          xacc, done, done8, out);
}

// Round 14
// 22.891 us; speedup vs baseline: 2.3544x; 2.3544x over previous
//
#include <hip/hip_runtime.h>

// B=8192, D=1024, C=90, K=16.
// R14 = R9 (best, 25.0 us) + two safe trims:
//  (1) bin_split: 180 blocks = (class, label-half). Each block ballot-scatters
//      only its half (16 serial ballot steps vs 32); the h=1 block recounts
//      half 0 with a count-only pass (no ballots) for its base. ~2x faster bin.
//  (2) quad_dots: R9 VERBATIM (wave = 4 same-class samples x D-half,
//      XCD-pinned classes via b&7, 4-k-group REDUCE16, pair epilogue).
//  (3) reduce_final: 1024 threads (3 loads/thread).
// No atomics anywhere (R6/R11/R13: device-scope atomic tails are 2-4x toxic).

#define B_SAMP  8192
#define K_SUB   16
#define C_CLS   90
#define LISTCAP 192             // per-class capacity (mean 91, ~10 sigma)
#define F4_ROW  256             // float4 per D=1024 row
#define TSLOT   192             // block slots per XCD group (2 quads each)
#define NBLK    (8 * TSLOT)     // 1536
#define NPART   (NBLK * 2)

// ws layout (bytes)
#define OFF_COUNTS 0            // 90 ints
#define OFF_LISTS  4096         // 90*192 ints
#define OFF_PART   (1u << 20)   // NPART floats

template <int CTRL>
__device__ __forceinline__ float dpp_qperm(float v) {
    return __int_as_float(__builtin_amdgcn_update_dpp(
        0, __float_as_int(v), CTRL, 0xF, 0xF, true));
}

__device__ __forceinline__ float dot8(float4 q0, float4 q1, float4 y0, float4 y1)
{
    float t = 0.0f;
    t = fmaf(y0.x, q0.x, t); t = fmaf(y0.y, q0.y, t);
    t = fmaf(y0.z, q0.z, t); t = fmaf(y0.w, q0.w, t);
    t = fmaf(y1.x, q1.x, t); t = fmaf(y1.y, q1.y, t);
    t = fmaf(y1.z, q1.z, t); t = fmaf(y1.w, q1.w, t);
    return t;
}

// 16-lane-group epilogue (verified R6-R13).
__device__ __forceinline__ float sample_loss16(float r, int kk)
{
    const float d = 1.0f - r;
    float S = d;
    S += __shfl_xor(S, 1, 64);
    S += __shfl_xor(S, 2, 64);
    S += __shfl_xor(S, 4, 64);
    S += __shfl_xor(S, 8, 64);
    float dmin = d;
    dmin = fminf(dmin, __shfl_xor(dmin, 1, 64));
    dmin = fminf(dmin, __shfl_xor(dmin, 2, 64));
    dmin = fminf(dmin, __shfl_xor(dmin, 4, 64));
    dmin = fminf(dmin, __shfl_xor(dmin, 8, 64));
    int cand = (d == dmin) ? kk : 99;      // first-min == jnp.argmin
    cand = min(cand, __shfl_xor(cand, 1, 64));
    cand = min(cand, __shfl_xor(cand, 2, 64));
    cand = min(cand, __shfl_xor(cand, 4, 64));
    cand = min(cand, __shfl_xor(cand, 8, 64));
    const float inv = 1.0f / S;
    float t = (kk == cand) ? (d * d * inv)            // term1
                           : ((1.0f - d * inv) * d);  // term2
    t += __shfl_xor(t, 1, 64);
    t += __shfl_xor(t, 2, 64);
    t += __shfl_xor(t, 4, 64);
    t += __shfl_xor(t, 8, 64);
    return t;
}

// ------- Kernel 1: split binning, block = (class, half of labels) -------
__global__ __launch_bounds__(256) void bin_split(
    const int* __restrict__ labels,
    int*       __restrict__ counts,
    int*       __restrict__ lists)
{
    const int c    = blockIdx.x >> 1;
    const int h    = blockIdx.x & 1;        // label half: [0,4096) or [4096,8192)
    const int tid  = threadIdx.x;
    const int wave = tid >> 6;
    const int lane = tid & 63;
    __shared__ int wcnt[4];
    __shared__ int b0_sh;

    const int4* lv = reinterpret_cast<const int4*>(labels);

    // h==1: count-only pass over half 0 (no ballots; cheap)
    if (h == 1) {
        int c0 = 0;
#pragma unroll
        for (int it = 0; it < 4; ++it) {
            const int4 l4 = lv[wave * 256 + it * 64 + lane];
            c0 += (l4.x == c) + (l4.y == c) + (l4.z == c) + (l4.w == c);
        }
#pragma unroll
        for (int off = 32; off > 0; off >>= 1) c0 += __shfl_xor(c0, off, 64);
        if (lane == 0) wcnt[wave] = c0;
        __syncthreads();
        if (tid == 0) b0_sh = wcnt[0] + wcnt[1] + wcnt[2] + wcnt[3];
        __syncthreads();
    } else {
        if (tid == 0) b0_sh = 0;
        __syncthreads();
    }
    const int hbase = b0_sh;

    // own half: standard 2-pass ballot scatter (4 int4-iters per wave)
    const int4* hv = lv + h * 1024;         // 4096 labels = 1024 int4

    int4 seg[4];
    int cnt = 0;
#pragma unroll
    for (int it = 0; it < 4; ++it) {
        seg[it] = hv[wave * 256 + it * 64 + lane];
        cnt += (seg[it].x == c) + (seg[it].y == c) + (seg[it].z == c) + (seg[it].w == c);
    }
#pragma unroll
    for (int off = 32; off > 0; off >>= 1) cnt += __shfl_xor(cnt, off, 64);
    if (lane == 0) wcnt[wave] = cnt;
    __syncthreads();

    int base = hbase;
    for (int w = 0; w < wave; ++w) base += wcnt[w];
    const int htotal = wcnt[0] + wcnt[1] + wcnt[2] + wcnt[3];

#pragma unroll
    for (int it = 0; it < 4; ++it) {
        const int idx0 = h * 4096 + (wave * 256 + it * 64 + lane) * 4;
        const int ls[4] = { seg[it].x, seg[it].y, seg[it].z, seg[it].w };
#pragma unroll
        for (int u = 0; u < 4; ++u) {
            const bool hit = (ls[u] == c);
            const unsigned long long m = __ballot(hit);
            if (hit) {
                const int p = base + (int)__popcll(m & ((1ull << lane) - 1ull));
                if (p < LISTCAP) lists[c * LISTCAP + p] = idx0 + u;
            }
            base += (int)__popcll(m);
        }
    }
    // h==1 knows the full count (hbase + its half's total)
    if (h == 1 && tid == 0) {
        const int total = hbase + htotal;
        counts[c] = (total <= LISTCAP) ? total : LISTCAP;
    }
}

// -------- Kernel 2: R9's quad_dots VERBATIM --------
__global__ __launch_bounds__(256) void quad_dots(
    const float* __restrict__ x,
    const float* __restrict__ centers,
    const int*   __restrict__ counts,
    const int*   __restrict__ lists,
    float*       __restrict__ partials)
{
    const int b    = blockIdx.x;
    const int g    = b & 7;                 // XCD group: classes c == g (mod 8)
    const int t    = b >> 3;
    const int tid  = threadIdx.x;
    const int wv   = tid >> 6;
    const int lane = tid & 63;
    const int pair = wv >> 1;               // 0 or 1: which quad
    const int h    = wv & 1;                // D-half

    __shared__ float sdots[4][4][16];       // [wave][sample][k]
    __shared__ float sgate[2][4];           // [pair][sample]

    // ---- 16-lane register scan: quad j -> (class, offset) ----
    const int cl  = g + 8 * lane;                       // lane<12 relevant
    const int n_l = (lane < 12 && cl < C_CLS) ? counts[cl] : 0;
    const int q_l = (n_l + 3) >> 2;                     // quads in this class
    int inc = q_l;
#pragma unroll
    for (int off = 1; off < 16; off <<= 1) {
        const int v = __shfl_up(inc, off, 64);
        if (lane >= off) inc += v;
    }
    const int Qg  = __shfl(inc, 15, 64);                // total quads in group
    const int exc = inc - q_l;

    const int j = 2 * t + pair;                         // this pair's quad id

    if (2 * t >= Qg) {                                  // dead block (uniform)
        if (tid < 2) partials[b * 2 + tid] = 0.0f;
        return;
    }

    const bool livepair = (j < Qg);                     // wave-uniform

    if (livepair) {
        const bool hit = (lane < 16) && (q_l > 0) && (j >= exc) && (j < inc);
        const unsigned long long m = __ballot(hit);
        const int ls   = (int)__ffsll(m) - 1;
        const int cls  = g + 8 * ls;
        const int qoff = j - __shfl(exc, ls, 64);
        const int cntc = __shfl(n_l, ls, 64);
        const int base = qoff * 4;                      // < cntc always

        const int4 grp = *reinterpret_cast<const int4*>(lists + cls * LISTCAP + base);
        int id[4];
        id[0] = grp.x;
        id[1] = (base + 1 < cntc) ? grp.y : grp.x;
        id[2] = (base + 2 < cntc) ? grp.z : grp.x;
        id[3] = (base + 3 < cntc) ? grp.w : grp.x;

        // x rows: this wave's D-half only -> x fetched exactly once per row.
        const float4* xv = reinterpret_cast<const float4*>(x);
        float4 xr[4][2];
#pragma unroll
        for (int s = 0; s < 4; ++s) {
            const size_t xo = (size_t)id[s] * F4_ROW + h * 128;
            xr[s][0] = xv[xo + lane];
            xr[s][1] = xv[xo + 64 + lane];
        }

        const float4* cb = reinterpret_cast<const float4*>(centers)
                         + (size_t)cls * (K_SUB * F4_ROW) + h * 128 + lane;

        const bool b0 = (lane & 1) != 0;
        const bool b1 = (lane & 2) != 0;
        const bool b2 = (lane & 4) != 0;
        const bool b3 = (lane & 8) != 0;
        const int kmap = 8 * (lane & 1) + 4 * ((lane >> 1) & 1)
                       + 2 * ((lane >> 2) & 1) + ((lane >> 3) & 1);

#define REDUCE16(A, OUT)                                                      \
    {                                                                         \
        _Pragma("unroll")                                                     \
        for (int jj = 0; jj < 8; ++jj) {                                      \
            const float send = b0 ? A[jj] : A[jj + 8];                        \
            const float recv = dpp_qperm<0xB1>(send);       /* xor 1 */       \
            A[jj] = (b0 ? A[jj + 8] : A[jj]) + recv;                          \
        }                                                                     \
        _Pragma("unroll")                                                     \
        for (int jj = 0; jj < 4; ++jj) {                                      \
            const float send = b1 ? A[jj] : A[jj + 4];                        \
            const float recv = dpp_qperm<0x4E>(send);       /* xor 2 */       \
            A[jj] = (b1 ? A[jj + 4] : A[jj]) + recv;                          \
        }                                                                     \
        _Pragma("unroll")                                                     \
        for (int jj = 0; jj < 2; ++jj) {                                      \
            const float send = b2 ? A[jj] : A[jj + 2];                        \
            const float recv = __shfl_xor(send, 4, 64);                       \
            A[jj] = (b2 ? A[jj + 2] : A[jj]) + recv;                          \
        }                                                                     \
        {                                                                     \
            const float send = b3 ? A[0] : A[1];                              \
            const float recv = __shfl_xor(send, 8, 64);                       \
            A[0] = (b3 ? A[1] : A[0]) + recv;                                 \
        }                                                                     \
        A[0] += __shfl_xor(A[0], 16, 64);                                     \
        A[0] += __shfl_xor(A[0], 32, 64);                                     \
        OUT = A[0];                                                           \
    }

        // 4 k-groups: only 16 accumulators live at a time (low VGPR).
#pragma unroll
        for (int kq = 0; kq < 4; ++kq) {
            float A[16];
#pragma unroll
            for (int kk = 0; kk < 4; ++kk) {
                const int k = kq * 4 + kk;
                const float4 q0 = cb[k * F4_ROW];
                const float4 q1 = cb[k * F4_ROW + 64];
                A[0 * 4 + kk] = dot8(q0, q1, xr[0][0], xr[0][1]);
                A[1 * 4 + kk] = dot8(q0, q1, xr[1][0], xr[1][1]);
                A[2 * 4 + kk] = dot8(q0, q1, xr[2][0], xr[2][1]);
                A[3 * 4 + kk] = dot8(q0, q1, xr[3][0], xr[3][1]);
            }
            float r;
            REDUCE16(A, r)
            if (lane < 16) sdots[wv][kmap >> 2][kq * 4 + (kmap & 3)] = r;
        }
#undef REDUCE16

        if (h == 0 && lane < 4)
            sgate[pair][lane] = (base + lane < cntc) ? 1.0f : 0.0f;
    } else {
        // dead pair: zero its sdots half + gates, then join the barrier
        if (lane < 16) {
#pragma unroll
            for (int s = 0; s < 4; ++s) sdots[wv][s][lane] = 0.0f;
        }
        if (h == 0 && lane < 4) sgate[pair][lane] = 0.0f;
    }

    __syncthreads();

    // epilogue: wave 0 -> pair 0, wave 1 -> pair 1
    if (wv < 2) {
        const int s  = lane >> 4;
        const int kk = lane & 15;
        const float r = sdots[wv * 2][s][kk] + sdots[wv * 2 + 1][s][kk];
        float wl = sample_loss16(r, kk) * sgate[wv][s];
        wl += __shfl_xor(wl, 16, 64);
        wl += __shfl_xor(wl, 32, 64);
        if (lane == 0) partials[b * 2 + wv] = wl;
    }
}

// ---------------- Kernel 3: final mean, 1024 threads ----------------
__global__ __launch_bounds__(1024) void reduce_final(
    const float* __restrict__ partials,
    float*       __restrict__ out)
{
    const int tid  = threadIdx.x;
    const int wave = tid >> 6;
    const int lane = tid & 63;
    float s = 0.0f;
#pragma unroll
    for (int r = 0; r < NPART / 1024; ++r) s += partials[r * 1024 + tid];
#pragma unroll
    for (int off = 32; off > 0; off >>= 1) s += __shfl_xor(s, off, 64);
    __shared__ float w[16];
    if (lane == 0) w[wave] = s;
    __syncthreads();
    if (wave == 0) {
        float v = (lane < 16) ? w[lane] : 0.0f;
#pragma unroll
        for (int off = 8; off > 0; off >>= 1) v += __shfl_xor(v, off, 64);
        if (lane == 0) out[0] = v * (1.0f / (float)B_SAMP);
    }
}

extern "C" void kernel_launch(void* const* d_in, const int* in_sizes, int n_in,
                              void* d_out, int out_size, void* d_ws, size_t ws_size,
                              hipStream_t stream)
{
    const float* x       = (const float*)d_in[0];
    const int*   labels  = (const int*)  d_in[1];
    const float* centers = (const float*)d_in[2];
    float*       out     = (float*)d_out;
    char*        ws      = (char*)d_ws;

    int*   counts = (int*)  (ws + OFF_COUNTS);
    int*   lists  = (int*)  (ws + OFF_LISTS);
    float* parts  = (float*)(ws + OFF_PART);

    bin_split   <<<C_CLS * 2, 256,  0, stream>>>(labels, counts, lists);
    quad_dots   <<<NBLK,      256,  0, stream>>>(x, centers, counts, lists, parts);
    reduce_final<<<1,         1024, 0, stream>>>(parts, out);
}